// Round 3
// baseline (158.947 us; speedup 1.0000x reference)
//
#include <hip/hip_runtime.h>

// K-winners-take-all: per row of [4096, 8192] f32, exactly k=410 largest -> 1.0.
// Ties at the k-th value broken by LOWER index (jax.lax.top_k stable semantics).
//
// R3 design: row in registers (8 x uint4 raw bits), candidates compacted to LDS.
//  1. load raw bits; count elements > 1.5 (Gaussian: ~547 >= k=410, 21-sigma safe)
//  2. compact candidate bits into LDS list via wave prefix-scan (~547 entries);
//     positive floats => raw bits are order-monotone, no f2ord needed
//  3. 4x 8-bit radix-select over the ~550-entry list (~2.2 visits/thread/pass);
//     ping-pong histograms: waves 1-3 zero next buf while wave 0 scans current
//  4. exact tie-break via per-thread equals-bitmask (any tie count m)
//  5. coalesced float4 mask write from registers
//  Fallback (never on this data): full register radix in f2ord domain.

#define E     8192
#define BLK   256
#define KACT  410
#define CAP   1024
#define NW    4

__device__ __forceinline__ unsigned f2ord(unsigned u) {
    return (u & 0x80000000u) ? ~u : (u | 0x80000000u);
}

// rank of equal-element (it,j) of thread t among all equals, ascending index.
// element index e = it*1024 + t*4 + j ; eqmask[t'] bit (it'*4+j') marks equals.
__device__ __noinline__ unsigned eq_rank(const unsigned* eqmask, int t, int it, int j) {
    const unsigned m_lt = (2u << (4 * it + 3)) - 1u;
    const unsigned m_eq = (1u << (4 * it + j)) - 1u;
    const unsigned m_gt = (1u << (4 * it)) - 1u;
    unsigned cnt = 0;
    for (int tp = 0; tp < BLK; ++tp) {
        unsigned em = eqmask[tp];
        unsigned msk = (tp < t) ? m_lt : ((tp == t) ? m_eq : m_gt);
        cnt += __popc(em & msk);
    }
    return cnt;
}

__global__ __launch_bounds__(BLK, 8)
void kwta_kernel(const float* __restrict__ x, float* __restrict__ out) {
    __shared__ unsigned ckey[CAP];          // 4 KB candidate bits
    __shared__ unsigned hist[2][NW][257];   // 8.2 KB ping-pong replicated hists
    __shared__ unsigned wsum[NW];
    __shared__ unsigned eqmask[BLK];        // 1 KB
    __shared__ unsigned s_prefix, s_kk;

    const int t    = threadIdx.x;
    const int lane = t & 63;
    const int wave = t >> 6;
    const size_t rowbase = (size_t)blockIdx.x * (size_t)E;
    const uint4* xin = reinterpret_cast<const uint4*>(x + rowbase);

    if (t == 0) { s_prefix = 0u; s_kk = KACT; }
    for (int i = t; i < NW * 257; i += BLK) (&hist[0][0][0])[i] = 0u;  // zero buf 0

    // ---- 1. load raw bits, count > pivot ----
    const float PIV = 1.5f;
    uint4 kv[8];
    unsigned c1 = 0;
    #pragma unroll
    for (int it = 0; it < 8; ++it) {
        uint4 v = xin[it * BLK + t];
        kv[it] = v;
        c1 += (__uint_as_float(v.x) > PIV) ? 1u : 0u;
        c1 += (__uint_as_float(v.y) > PIV) ? 1u : 0u;
        c1 += (__uint_as_float(v.z) > PIV) ? 1u : 0u;
        c1 += (__uint_as_float(v.w) > PIV) ? 1u : 0u;
    }
    // wave inclusive scan of per-thread candidate count
    unsigned inc = c1;
    #pragma unroll
    for (int d = 1; d < 64; d <<= 1) {
        unsigned o = __shfl_up(inc, d);
        if (lane >= d) inc += o;
    }
    if (lane == 63) wsum[wave] = inc;
    __syncthreads();
    unsigned base = inc - c1;
    #pragma unroll
    for (int w = 0; w < NW; ++w) base += (w < wave) ? wsum[w] : 0u;
    const unsigned n1 = wsum[0] + wsum[1] + wsum[2] + wsum[3];
    const bool usec = (n1 >= KACT) && (n1 <= CAP);   // block-uniform

    // ---- 2. compact candidates (raw bits) into LDS ----
    if (usec) {
        unsigned pos = base;
        #pragma unroll
        for (int it = 0; it < 8; ++it) {
            uint4 v = kv[it];
            unsigned a[4] = {v.x, v.y, v.z, v.w};
            #pragma unroll
            for (int j = 0; j < 4; ++j)
                if (__uint_as_float(a[j]) > PIV) ckey[pos++] = a[j];
        }
    }
    __syncthreads();

    // ---- 3. radix select (4 x 8-bit passes, MSB first) ----
    const unsigned ncand = usec ? n1 : 0u;
    #pragma unroll 1
    for (int p = 0; p < 4; ++p) {
        const int cur = p & 1, nxt = cur ^ 1;
        const int shift = 24 - 8 * p;
        const unsigned fixedmask = (p == 0) ? 0u : (0xFFFFFFFFu << (shift + 8));
        const unsigned pref = s_prefix;
        if (usec) {
            for (unsigned i = t; i < ncand; i += BLK) {
                unsigned key = ckey[i];
                if ((key & fixedmask) == pref)
                    atomicAdd(&hist[cur][wave][(key >> shift) & 255u], 1u);
            }
        } else {   // fallback: full register scan in f2ord domain
            #pragma unroll
            for (int it = 0; it < 8; ++it) {
                uint4 v = kv[it];
                unsigned a[4] = {v.x, v.y, v.z, v.w};
                #pragma unroll
                for (int j = 0; j < 4; ++j) {
                    unsigned key = f2ord(a[j]);
                    if ((key & fixedmask) == pref)
                        atomicAdd(&hist[cur][wave][(key >> shift) & 255u], 1u);
                }
            }
        }
        __syncthreads();
        if (wave == 0) {
            const int b = lane * 4;
            unsigned h0 = 0, h1 = 0, h2 = 0, h3 = 0;
            #pragma unroll
            for (int r = 0; r < NW; ++r) {
                h0 += hist[cur][r][b];     h1 += hist[cur][r][b + 1];
                h2 += hist[cur][r][b + 2]; h3 += hist[cur][r][b + 3];
            }
            unsigned local = h0 + h1 + h2 + h3;
            unsigned run = local;
            #pragma unroll
            for (int d = 1; d < 64; d <<= 1) {
                unsigned o = __shfl_down(run, d);
                run += (lane + d < 64) ? o : 0u;
            }
            const unsigned tail = run - local;   // suffix over higher lanes
            const unsigned kk = s_kk;
            const unsigned s3 = tail + h3;
            const unsigned s2 = s3 + h2;
            const unsigned s1 = s2 + h1;
            const unsigned s0 = s1 + h0;
            unsigned nb = 0, nk = 0; bool f = false;
            if      (s0 >= kk && s1   < kk) { f = true; nb = b + 0; nk = kk - s1; }
            else if (s1 >= kk && s2   < kk) { f = true; nb = b + 1; nk = kk - s2; }
            else if (s2 >= kk && s3   < kk) { f = true; nb = b + 2; nk = kk - s3; }
            else if (s3 >= kk && tail < kk) { f = true; nb = b + 3; nk = kk - tail; }
            if (f) { s_prefix = pref | ((unsigned)nb << shift); s_kk = nk; }
        } else {
            for (int i = t - 64; i < NW * 257; i += 3 * 64)   // zero next buffer
                (&hist[nxt][0][0])[i] = 0u;
        }
        __syncthreads();
    }
    const unsigned T  = s_prefix;   // k-th largest key (raw bits if usec, f2ord else)
    const unsigned kk = s_kk;       // winners among elements == T

    // ---- 4. equals bitmask (exact tie-break, any m) ----
    unsigned myeq = 0u;
    #pragma unroll
    for (int it = 0; it < 8; ++it) {
        uint4 v = kv[it];
        unsigned a[4] = {v.x, v.y, v.z, v.w};
        #pragma unroll
        for (int j = 0; j < 4; ++j) {
            unsigned key = usec ? a[j] : f2ord(a[j]);
            myeq |= (key == T ? 1u : 0u) << (it * 4 + j);
        }
    }
    eqmask[t] = myeq;
    unsigned pm = __popc(myeq);
    #pragma unroll
    for (int d = 1; d < 64; d <<= 1) pm += __shfl_down(pm, d);
    __syncthreads();           // wsum reuse: ensure prior readers done
    if (lane == 0) wsum[wave] = pm;
    __syncthreads();
    const unsigned m = wsum[0] + wsum[1] + wsum[2] + wsum[3];
    const bool allwin = (kk == m);   // common: unique k-th value

    // ---- 5. coalesced mask write ----
    float4* o = reinterpret_cast<float4*>(out + rowbase);
    if (usec) {
        const float Tf = __uint_as_float(T);
        #pragma unroll
        for (int it = 0; it < 8; ++it) {
            uint4 v = kv[it];
            unsigned a[4] = {v.x, v.y, v.z, v.w};
            float rs[4];
            #pragma unroll
            for (int j = 0; j < 4; ++j) {
                float xf = __uint_as_float(a[j]);
                float val;
                if (xf > Tf)       val = 1.0f;    // Tf >= 1.5 > 0: total order, no ±0 hazard
                else if (a[j] != T) val = 0.0f;
                else if (allwin)    val = 1.0f;
                else                val = (eq_rank(eqmask, t, it, j) < kk) ? 1.0f : 0.0f;
                rs[j] = val;
            }
            float4 r; r.x = rs[0]; r.y = rs[1]; r.z = rs[2]; r.w = rs[3];
            o[it * BLK + t] = r;
        }
    } else {
        #pragma unroll
        for (int it = 0; it < 8; ++it) {
            uint4 v = kv[it];
            unsigned a[4] = {v.x, v.y, v.z, v.w};
            float rs[4];
            #pragma unroll
            for (int j = 0; j < 4; ++j) {
                unsigned key = f2ord(a[j]);
                float val;
                if (key > T)       val = 1.0f;
                else if (key != T) val = 0.0f;
                else if (allwin)   val = 1.0f;
                else               val = (eq_rank(eqmask, t, it, j) < kk) ? 1.0f : 0.0f;
                rs[j] = val;
            }
            float4 r; r.x = rs[0]; r.y = rs[1]; r.z = rs[2]; r.w = rs[3];
            o[it * BLK + t] = r;
        }
    }
}

extern "C" void kernel_launch(void* const* d_in, const int* in_sizes, int n_in,
                              void* d_out, int out_size, void* d_ws, size_t ws_size,
                              hipStream_t stream) {
    const float* x = (const float*)d_in[0];
    float* out = (float*)d_out;
    const int rows = in_sizes[0] / E;   // 4096
    kwta_kernel<<<dim3(rows), dim3(BLK), 0, stream>>>(x, out);
}

// Round 4
// 50.772 us; speedup vs baseline: 3.1306x; 3.1306x over previous
//
#include <hip/hip_runtime.h>

// K-winners-take-all: per row of [4096, 8192] f32, exactly k=410 largest -> 1.0.
// Ties at the k-th value broken by LOWER index (jax.lax.top_k stable semantics).
//
// R4: row in registers (8 x uint4, launch_bounds(256,4) -- (256,8) forced VGPR=32
// and spilled the row to scratch, doubling HBM traffic in R3).
// Selection = ONE histogram pass:
//   candidates are x > 1.5 (N(0,1): ~547 >= k=410, 21-sigma margin). Their raw
//   bits lie in [0x3FC00000, ~0x40C00000): bin = (bits-0x3FC00000)>>13, 2048
//   monotone bins (~0.001 wide at threshold). ~550 atomics over 2048 bins.
//   Hierarchical suffix-sum -> threshold bin b + kkb winners inside it.
//   Collect bin-b elements (expected ~1, cap 64) -> exact 64-lane rank select.
// Exact tie-break via per-thread equals-bitmask. f2ord register-radix fallback
// (never taken on this data) keeps correctness for arbitrary inputs.

#define E     8192
#define BLK   256
#define KACT  410
#define NBINS 2048
#define SHIFTB 13
#define BASEB 0x3FC00000u   // bits of 1.5f
#define CCAP  64

__device__ __forceinline__ unsigned f2ord(unsigned u) {
    return (u & 0x80000000u) ? ~u : (u | 0x80000000u);
}

// rank of equal-element (it,j) of thread t among all equals, ascending index.
// element index e = it*1024 + t*4 + j ; eqmask[t'] bit (it'*4+j') marks equals.
__device__ __noinline__ unsigned eq_rank(const unsigned* eqmask, int t, int it, int j) {
    const unsigned m_lt = (2u << (4 * it + 3)) - 1u;
    const unsigned m_eq = (1u << (4 * it + j)) - 1u;
    const unsigned m_gt = (1u << (4 * it)) - 1u;
    unsigned cnt = 0;
    for (int tp = 0; tp < BLK; ++tp) {
        unsigned em = eqmask[tp];
        unsigned msk = (tp < t) ? m_lt : ((tp == t) ? m_eq : m_gt);
        cnt += __popc(em & msk);
    }
    return cnt;
}

__global__ __launch_bounds__(BLK, 4)
void kwta_kernel(const float* __restrict__ x, float* __restrict__ out) {
    __shared__ unsigned hist[NBINS];      // 8 KB
    __shared__ unsigned clist[CCAP];
    __shared__ unsigned eqmask[BLK];      // 1 KB
    __shared__ unsigned wsum[4];
    __shared__ unsigned s_bin, s_kkb, s_T, s_kkT, s_cnum;
    __shared__ unsigned s_prefix, s_kk;   // fallback radix state

    const int t    = threadIdx.x;
    const int lane = t & 63;
    const int wave = t >> 6;
    const size_t rowbase = (size_t)blockIdx.x * (size_t)E;
    const uint4* xin = reinterpret_cast<const uint4*>(x + rowbase);

    for (int i = t; i < NBINS; i += BLK) hist[i] = 0u;
    if (t == 0) { s_cnum = 0u; s_prefix = 0u; s_kk = KACT; }

    // ---- A. load row -> registers, count candidates (> 1.5) ----
    uint4 kv[8];
    unsigned c1 = 0;
    #pragma unroll
    for (int it = 0; it < 8; ++it) {
        uint4 v = xin[it * BLK + t];
        kv[it] = v;
        c1 += (__uint_as_float(v.x) > 1.5f) ? 1u : 0u;
        c1 += (__uint_as_float(v.y) > 1.5f) ? 1u : 0u;
        c1 += (__uint_as_float(v.z) > 1.5f) ? 1u : 0u;
        c1 += (__uint_as_float(v.w) > 1.5f) ? 1u : 0u;
    }
    unsigned r = c1;
    #pragma unroll
    for (int d = 1; d < 64; d <<= 1) r += __shfl_down(r, d);
    if (lane == 0) wsum[wave] = r;
    __syncthreads();                                            // b1
    const unsigned n1 = wsum[0] + wsum[1] + wsum[2] + wsum[3];

    bool fb = (n1 < KACT);     // fallback if threshold could be <= 1.5
    bool rawdom = false;
    unsigned T = 0, kkT = 0;

    if (!fb) {
        // ---- B. histogram from registers ----
        #pragma unroll
        for (int it = 0; it < 8; ++it) {
            uint4 v = kv[it];
            unsigned a[4] = {v.x, v.y, v.z, v.w};
            #pragma unroll
            for (int j = 0; j < 4; ++j) {
                if (__uint_as_float(a[j]) > 1.5f) {
                    unsigned b = (a[j] - BASEB) >> SHIFTB;
                    b = (b > NBINS - 1u) ? (NBINS - 1u) : b;
                    atomicAdd(&hist[b], 1u);
                }
            }
        }
        __syncthreads();                                        // b2

        // ---- C. hierarchical suffix-sum over 2048 bins ----
        unsigned h[8]; unsigned local = 0;
        #pragma unroll
        for (int j = 0; j < 8; ++j) { h[j] = hist[8 * t + j]; local += h[j]; }
        unsigned run = local;
        #pragma unroll
        for (int d = 1; d < 64; d <<= 1) {
            unsigned o = __shfl_down(run, d);
            run += (lane + d < 64) ? o : 0u;
        }
        const unsigned tail = run - local;     // lanes above me, my wave
        if (lane == 0) wsum[wave] = run;       // wave total
        __syncthreads();                                        // b3
        unsigned suf = tail;
        #pragma unroll
        for (int w = 0; w < 4; ++w) suf += (w > wave) ? wsum[w] : 0u;
        #pragma unroll
        for (int j = 7; j >= 0; --j) {         // suf = count in bins > (8t+j)
            if (suf < KACT && suf + h[j] >= KACT) {
                s_bin = (unsigned)(8 * t + j); s_kkb = KACT - suf;
            }
            suf += h[j];
        }
        __syncthreads();                                        // b4
        const unsigned b = s_bin, kkb = s_kkb;

        // ---- D. collect elements in threshold bin ----
        #pragma unroll
        for (int it = 0; it < 8; ++it) {
            uint4 v = kv[it];
            unsigned a[4] = {v.x, v.y, v.z, v.w};
            #pragma unroll
            for (int j = 0; j < 4; ++j) {
                if (__uint_as_float(a[j]) > 1.5f) {
                    unsigned bb = (a[j] - BASEB) >> SHIFTB;
                    bb = (bb > NBINS - 1u) ? (NBINS - 1u) : bb;
                    if (bb == b) {
                        unsigned p = atomicAdd(&s_cnum, 1u);
                        if (p < CCAP) clist[p] = a[j];
                    }
                }
            }
        }
        __syncthreads();                                        // b5
        const unsigned cn = s_cnum;
        if (cn <= CCAP) {
            // ---- E. exact select within bin (64-lane rank) ----
            if (wave == 0) {
                unsigned key = (lane < (int)cn) ? clist[lane] : 0u;
                unsigned gt = 0, eq = 0;
                for (unsigned jj = 0; jj < cn; ++jj) {
                    unsigned kj = clist[jj];
                    gt += (kj > key) ? 1u : 0u;
                    eq += (kj == key) ? 1u : 0u;
                }
                if (lane < (int)cn && gt < kkb && gt + eq >= kkb) {
                    s_T = key; s_kkT = kkb - gt;   // all writers hold same value
                }
            }
            __syncthreads();                                    // b6
            T = s_T; kkT = s_kkT; rawdom = true;
        } else {
            fb = true;   // adversarial pile-up in one bin: exact fallback
        }
    }

    if (fb) {
        // ---- fallback: full 4x8-bit radix over f2ord keys (exact, any data) ----
        #pragma unroll 1
        for (int p = 0; p < 4; ++p) {
            const int shift = 24 - 8 * p;
            const unsigned fixedmask = (p == 0) ? 0u : (0xFFFFFFFFu << (shift + 8));
            hist[t] = 0u;
            __syncthreads();
            const unsigned pref = s_prefix;
            #pragma unroll
            for (int it = 0; it < 8; ++it) {
                uint4 v = kv[it];
                unsigned a[4] = {v.x, v.y, v.z, v.w};
                #pragma unroll
                for (int j = 0; j < 4; ++j) {
                    unsigned key = f2ord(a[j]);
                    if ((key & fixedmask) == pref)
                        atomicAdd(&hist[(key >> shift) & 255u], 1u);
                }
            }
            __syncthreads();
            if (wave == 0) {
                const int b4 = lane * 4;
                unsigned h0 = hist[b4], h1 = hist[b4 + 1], h2 = hist[b4 + 2], h3 = hist[b4 + 3];
                unsigned local = h0 + h1 + h2 + h3;
                unsigned run = local;
                #pragma unroll
                for (int d = 1; d < 64; d <<= 1) {
                    unsigned o = __shfl_down(run, d);
                    run += (lane + d < 64) ? o : 0u;
                }
                const unsigned tail = run - local;
                const unsigned kk = s_kk;
                const unsigned s3 = tail + h3;
                const unsigned s2 = s3 + h2;
                const unsigned s1 = s2 + h1;
                const unsigned s0 = s1 + h0;
                if      (s0 >= kk && s1   < kk) { s_prefix = pref | ((unsigned)(b4 + 0) << shift); s_kk = kk - s1; }
                else if (s1 >= kk && s2   < kk) { s_prefix = pref | ((unsigned)(b4 + 1) << shift); s_kk = kk - s2; }
                else if (s2 >= kk && s3   < kk) { s_prefix = pref | ((unsigned)(b4 + 2) << shift); s_kk = kk - s3; }
                else if (s3 >= kk && tail < kk) { s_prefix = pref | ((unsigned)(b4 + 3) << shift); s_kk = kk - tail; }
            }
            __syncthreads();
        }
        T = s_prefix; kkT = s_kk; rawdom = false;
    }

    // ---- F. equals bitmask -> m, allwin ----
    unsigned myeq = 0u;
    #pragma unroll
    for (int it = 0; it < 8; ++it) {
        uint4 v = kv[it];
        unsigned a[4] = {v.x, v.y, v.z, v.w};
        #pragma unroll
        for (int j = 0; j < 4; ++j) {
            unsigned key = rawdom ? a[j] : f2ord(a[j]);
            myeq |= (key == T ? 1u : 0u) << (it * 4 + j);
        }
    }
    eqmask[t] = myeq;
    unsigned pm = __popc(myeq);
    #pragma unroll
    for (int d = 1; d < 64; d <<= 1) pm += __shfl_down(pm, d);
    if (lane == 0) wsum[wave] = pm;
    __syncthreads();                                            // b7
    const unsigned m = wsum[0] + wsum[1] + wsum[2] + wsum[3];
    const bool allwin = (kkT == m);

    // ---- G. coalesced mask write ----
    float4* o = reinterpret_cast<float4*>(out + rowbase);
    if (rawdom) {
        const float Tf = __uint_as_float(T);
        #pragma unroll
        for (int it = 0; it < 8; ++it) {
            uint4 v = kv[it];
            unsigned a[4] = {v.x, v.y, v.z, v.w};
            float rs[4];
            #pragma unroll
            for (int j = 0; j < 4; ++j) {
                float xf = __uint_as_float(a[j]);
                float val;
                if (xf > Tf)        val = 1.0f;   // Tf > 1.5: no ±0/NaN hazard
                else if (a[j] != T) val = 0.0f;
                else if (allwin)    val = 1.0f;
                else                val = (eq_rank(eqmask, t, it, j) < kkT) ? 1.0f : 0.0f;
                rs[j] = val;
            }
            float4 rr; rr.x = rs[0]; rr.y = rs[1]; rr.z = rs[2]; rr.w = rs[3];
            o[it * BLK + t] = rr;
        }
    } else {
        #pragma unroll
        for (int it = 0; it < 8; ++it) {
            uint4 v = kv[it];
            unsigned a[4] = {v.x, v.y, v.z, v.w};
            float rs[4];
            #pragma unroll
            for (int j = 0; j < 4; ++j) {
                unsigned key = f2ord(a[j]);
                float val;
                if (key > T)       val = 1.0f;
                else if (key != T) val = 0.0f;
                else if (allwin)   val = 1.0f;
                else               val = (eq_rank(eqmask, t, it, j) < kkT) ? 1.0f : 0.0f;
                rs[j] = val;
            }
            float4 rr; rr.x = rs[0]; rr.y = rs[1]; rr.z = rs[2]; rr.w = rs[3];
            o[it * BLK + t] = rr;
        }
    }
}

extern "C" void kernel_launch(void* const* d_in, const int* in_sizes, int n_in,
                              void* d_out, int out_size, void* d_ws, size_t ws_size,
                              hipStream_t stream) {
    const float* x = (const float*)d_in[0];
    float* out = (float*)d_out;
    const int rows = in_sizes[0] / E;   // 4096
    kwta_kernel<<<dim3(rows), dim3(BLK), 0, stream>>>(x, out);
}

// Round 5
// 44.926 us; speedup vs baseline: 3.5380x; 1.1301x over previous
//
#include <hip/hip_runtime.h>

// K-winners-take-all: per row of [4096, 8192] f32, exactly k=410 largest -> 1.0.
// Ties at the k-th value broken by LOWER index (jax.lax.top_k stable semantics).
//
// R5: row in registers (8 x uint4, launch_bounds(256,4): R3 proved tighter bounds
// spill the row and double HBM traffic).
//  - fused load+count+histogram single register pass (one barrier saved)
//  - 2048 monotone bins over candidate bits (>1.5; N(0,1): ~547 >= k, 21 sigma)
//  - threshold bin -> exact in-bin rank select; allwin (unique k-th value) known
//    there for free (all equals-to-T live in the same bin), so the eqmask
//    tie-break phase is SKIPPED in the common path
//  - NON-TEMPORAL output stores: output (131 MB) no longer evicts the input
//    (128 MiB) from the 256 MiB L3 -> FETCH ~0 on warm replays
//  - exact fallbacks kept: f2ord register radix (n1<k) and eqmask tie-break

#define E      8192
#define BLK    256
#define KACT   410
#define NBINS  2048
#define SHIFTB 13
#define BASEB  0x3FC00000u   // bits of 1.5f
#define CCAP   64

typedef float f32x4 __attribute__((ext_vector_type(4)));

__device__ __forceinline__ unsigned f2ord(unsigned u) {
    return (u & 0x80000000u) ? ~u : (u | 0x80000000u);
}

// rank of equal-element (it,j) of thread t among all equals, ascending index.
// element index e = it*1024 + t*4 + j ; eqmask[t'] bit (it'*4+j') marks equals.
__device__ __noinline__ unsigned eq_rank(const unsigned* eqmask, int t, int it, int j) {
    const unsigned m_lt = (2u << (4 * it + 3)) - 1u;
    const unsigned m_eq = (1u << (4 * it + j)) - 1u;
    const unsigned m_gt = (1u << (4 * it)) - 1u;
    unsigned cnt = 0;
    for (int tp = 0; tp < BLK; ++tp) {
        unsigned em = eqmask[tp];
        unsigned msk = (tp < t) ? m_lt : ((tp == t) ? m_eq : m_gt);
        cnt += __popc(em & msk);
    }
    return cnt;
}

__global__ __launch_bounds__(BLK, 4)
void kwta_kernel(const float* __restrict__ x, float* __restrict__ out) {
    __shared__ unsigned hist[NBINS];      // 8 KB
    __shared__ unsigned clist[CCAP];
    __shared__ unsigned eqmask[BLK];      // 1 KB
    __shared__ unsigned wsumA[4], wsumB[4];
    __shared__ unsigned s_bin, s_kkb, s_T, s_kkT, s_aw, s_cnum;
    __shared__ unsigned s_prefix, s_kk;   // fallback radix state

    const int t    = threadIdx.x;
    const int lane = t & 63;
    const int wave = t >> 6;
    const size_t rowbase = (size_t)blockIdx.x * (size_t)E;
    const uint4* xin = reinterpret_cast<const uint4*>(x + rowbase);

    // issue row loads first; they fly while we zero the histogram
    uint4 kv[8];
    #pragma unroll
    for (int it = 0; it < 8; ++it) kv[it] = xin[it * BLK + t];

    for (int i = t; i < NBINS; i += BLK) hist[i] = 0u;
    if (t == 0) { s_cnum = 0u; s_prefix = 0u; s_kk = KACT; }
    __syncthreads();                                            // b0: hist zeroed

    // ---- A+B fused: count candidates (> 1.5) and histogram them ----
    unsigned c1 = 0;
    #pragma unroll
    for (int it = 0; it < 8; ++it) {
        uint4 v = kv[it];
        unsigned a[4] = {v.x, v.y, v.z, v.w};
        #pragma unroll
        for (int j = 0; j < 4; ++j) {
            if (__uint_as_float(a[j]) > 1.5f) {
                ++c1;
                unsigned b = (a[j] - BASEB) >> SHIFTB;
                b = (b > NBINS - 1u) ? (NBINS - 1u) : b;
                atomicAdd(&hist[b], 1u);
            }
        }
    }
    unsigned r = c1;
    #pragma unroll
    for (int d = 1; d < 64; d <<= 1) r += __shfl_down(r, d);
    if (lane == 0) wsumA[wave] = r;
    __syncthreads();                                            // b1: hist + wsumA
    const unsigned n1 = wsumA[0] + wsumA[1] + wsumA[2] + wsumA[3];

    bool fb = (n1 < KACT);     // threshold could be <= 1.5 -> exact fallback
    bool rawdom = false, allwin = false;
    unsigned T = 0, kkT = 0;

    if (!fb) {
        // ---- C. hierarchical suffix-sum over 2048 bins ----
        unsigned h[8]; unsigned local = 0;
        #pragma unroll
        for (int j = 0; j < 8; ++j) { h[j] = hist[8 * t + j]; local += h[j]; }
        unsigned run = local;
        #pragma unroll
        for (int d = 1; d < 64; d <<= 1) {
            unsigned o = __shfl_down(run, d);
            run += (lane + d < 64) ? o : 0u;
        }
        const unsigned tail = run - local;
        if (lane == 0) wsumB[wave] = run;
        __syncthreads();                                        // b2
        unsigned suf = tail;
        #pragma unroll
        for (int w = 0; w < 4; ++w) suf += (w > wave) ? wsumB[w] : 0u;
        #pragma unroll
        for (int j = 7; j >= 0; --j) {        // suf = count in bins > (8t+j)
            if (suf < KACT && suf + h[j] >= KACT) {
                s_bin = (unsigned)(8 * t + j); s_kkb = KACT - suf;
            }
            suf += h[j];
        }
        __syncthreads();                                        // b3
        const unsigned b = s_bin, kkb = s_kkb;

        // ---- D. collect threshold-bin elements (expected ~1-3, cap 64) ----
        const unsigned keylo = BASEB + (b << SHIFTB);
        const unsigned range = (b == NBINS - 1u) ? (0x80000000u - keylo)
                                                 : (1u << SHIFTB);
        #pragma unroll
        for (int it = 0; it < 8; ++it) {
            uint4 v = kv[it];
            unsigned a[4] = {v.x, v.y, v.z, v.w};
            #pragma unroll
            for (int j = 0; j < 4; ++j) {
                if (a[j] - keylo < range) {     // monotone in-bin test (see R4 notes)
                    unsigned p = atomicAdd(&s_cnum, 1u);
                    if (p < CCAP) clist[p] = a[j];
                }
            }
        }
        __syncthreads();                                        // b4
        const unsigned cn = s_cnum;
        if (cn <= CCAP) {
            // ---- E. exact in-bin rank select; allwin for free (m == eq) ----
            if (wave == 0) {
                unsigned key = (lane < (int)cn) ? clist[lane] : 0u;
                unsigned gt = 0, eq = 0;
                for (unsigned jj = 0; jj < cn; ++jj) {
                    unsigned kj = clist[jj];
                    gt += (kj > key) ? 1u : 0u;
                    eq += (kj == key) ? 1u : 0u;
                }
                if (lane < (int)cn && gt < kkb && gt + eq >= kkb) {
                    s_T = key; s_kkT = kkb - gt;
                    s_aw = (kkb - gt == eq) ? 1u : 0u;   // all ties win?
                }
            }
            __syncthreads();                                    // b5
            T = s_T; kkT = s_kkT; allwin = (s_aw != 0u); rawdom = true;
        } else {
            fb = true;   // adversarial pile-up in one bin
        }
    }

    if (fb) {
        // ---- exact fallback: 4x8-bit radix over f2ord keys ----
        #pragma unroll 1
        for (int p = 0; p < 4; ++p) {
            const int shift = 24 - 8 * p;
            const unsigned fixedmask = (p == 0) ? 0u : (0xFFFFFFFFu << (shift + 8));
            hist[t] = 0u;
            __syncthreads();
            const unsigned pref = s_prefix;
            #pragma unroll
            for (int it = 0; it < 8; ++it) {
                uint4 v = kv[it];
                unsigned a[4] = {v.x, v.y, v.z, v.w};
                #pragma unroll
                for (int j = 0; j < 4; ++j) {
                    unsigned key = f2ord(a[j]);
                    if ((key & fixedmask) == pref)
                        atomicAdd(&hist[(key >> shift) & 255u], 1u);
                }
            }
            __syncthreads();
            if (wave == 0) {
                const int b4 = lane * 4;
                unsigned h0 = hist[b4], h1 = hist[b4 + 1], h2 = hist[b4 + 2], h3 = hist[b4 + 3];
                unsigned local = h0 + h1 + h2 + h3;
                unsigned run = local;
                #pragma unroll
                for (int d = 1; d < 64; d <<= 1) {
                    unsigned o = __shfl_down(run, d);
                    run += (lane + d < 64) ? o : 0u;
                }
                const unsigned tail = run - local;
                const unsigned kk = s_kk;
                const unsigned s3 = tail + h3;
                const unsigned s2 = s3 + h2;
                const unsigned s1 = s2 + h1;
                const unsigned s0 = s1 + h0;
                if      (s0 >= kk && s1   < kk) { s_prefix = pref | ((unsigned)(b4 + 0) << shift); s_kk = kk - s1; }
                else if (s1 >= kk && s2   < kk) { s_prefix = pref | ((unsigned)(b4 + 1) << shift); s_kk = kk - s2; }
                else if (s2 >= kk && s3   < kk) { s_prefix = pref | ((unsigned)(b4 + 2) << shift); s_kk = kk - s3; }
                else if (s3 >= kk && tail < kk) { s_prefix = pref | ((unsigned)(b4 + 3) << shift); s_kk = kk - tail; }
            }
            __syncthreads();
        }
        T = s_prefix; kkT = s_kk; rawdom = false;
    }

    // ---- tie path only (rare): build eqmask, compute m ----
    if (fb || !allwin) {
        unsigned myeq = 0u;
        #pragma unroll
        for (int it = 0; it < 8; ++it) {
            uint4 v = kv[it];
            unsigned a[4] = {v.x, v.y, v.z, v.w};
            #pragma unroll
            for (int j = 0; j < 4; ++j) {
                unsigned key = rawdom ? a[j] : f2ord(a[j]);
                myeq |= (key == T ? 1u : 0u) << (it * 4 + j);
            }
        }
        eqmask[t] = myeq;
        unsigned pm = __popc(myeq);
        #pragma unroll
        for (int d = 1; d < 64; d <<= 1) pm += __shfl_down(pm, d);
        if (lane == 0) wsumB[wave] = pm;
        __syncthreads();
        const unsigned m = wsumB[0] + wsumB[1] + wsumB[2] + wsumB[3];
        if (fb) allwin = (kkT == m);
    }

    // ---- write mask (non-temporal: don't evict input from L3) ----
    f32x4* o = reinterpret_cast<f32x4*>(out + rowbase);
    if (rawdom && allwin) {
        const float Tf = __uint_as_float(T);
        #pragma unroll
        for (int it = 0; it < 8; ++it) {
            uint4 v = kv[it];
            f32x4 rr;
            rr.x = (__uint_as_float(v.x) >= Tf) ? 1.0f : 0.0f;
            rr.y = (__uint_as_float(v.y) >= Tf) ? 1.0f : 0.0f;
            rr.z = (__uint_as_float(v.z) >= Tf) ? 1.0f : 0.0f;
            rr.w = (__uint_as_float(v.w) >= Tf) ? 1.0f : 0.0f;
            __builtin_nontemporal_store(rr, o + it * BLK + t);
        }
    } else if (rawdom) {
        const float Tf = __uint_as_float(T);
        #pragma unroll
        for (int it = 0; it < 8; ++it) {
            uint4 v = kv[it];
            unsigned a[4] = {v.x, v.y, v.z, v.w};
            float rs[4];
            #pragma unroll
            for (int j = 0; j < 4; ++j) {
                float xf = __uint_as_float(a[j]);
                float val;
                if (xf > Tf)        val = 1.0f;
                else if (a[j] != T) val = 0.0f;
                else                val = (eq_rank(eqmask, t, it, j) < kkT) ? 1.0f : 0.0f;
                rs[j] = val;
            }
            f32x4 rr; rr.x = rs[0]; rr.y = rs[1]; rr.z = rs[2]; rr.w = rs[3];
            __builtin_nontemporal_store(rr, o + it * BLK + t);
        }
    } else {
        #pragma unroll
        for (int it = 0; it < 8; ++it) {
            uint4 v = kv[it];
            unsigned a[4] = {v.x, v.y, v.z, v.w};
            float rs[4];
            #pragma unroll
            for (int j = 0; j < 4; ++j) {
                unsigned key = f2ord(a[j]);
                float val;
                if (key > T)       val = 1.0f;
                else if (key != T) val = 0.0f;
                else if (allwin)   val = 1.0f;
                else               val = (eq_rank(eqmask, t, it, j) < kkT) ? 1.0f : 0.0f;
                rs[j] = val;
            }
            f32x4 rr; rr.x = rs[0]; rr.y = rs[1]; rr.z = rs[2]; rr.w = rs[3];
            __builtin_nontemporal_store(rr, o + it * BLK + t);
        }
    }
}

extern "C" void kernel_launch(void* const* d_in, const int* in_sizes, int n_in,
                              void* d_out, int out_size, void* d_ws, size_t ws_size,
                              hipStream_t stream) {
    const float* x = (const float*)d_in[0];
    float* out = (float*)d_out;
    const int rows = in_sizes[0] / E;   // 4096
    kwta_kernel<<<dim3(rows), dim3(BLK), 0, stream>>>(x, out);
}